// Round 7
// baseline (323.478 us; speedup 1.0000x reference)
//
#include <hip/hip_runtime.h>
#include <hip/hip_bf16.h>
#include <stdint.h>

// ---------------------------------------------------------------------------
// CrossAttention: out = concat([rgb, 0.5 * softmax((rgb Wq)(freq Wk)^T/sqrt(D)) @ freq], -1)
// B=8, N=2048, D=E=1024.
// GEMMs: 256^2 8-phase template, BK=64, 8 waves, 128KiB LDS 2-tile double
// buffer, st_16x32 XOR swizzle (T2, verified: bank conflicts = 0), counted
// vmcnt(8) with 4-5-phase issue->wait gap (T3+T4), setprio (T5), XCD swizzle (T1).
//
// d_out rows (2048 f32 = 4096 bf16 slots, m = b*2048+n):
//   cast_copy:      f32 [0:1024)  = rgb  (cols), slots [0:2048)
//   after gemm<0>:  Q bf16 slots [2048:3072], K bf16 slots [3072:4096]
//   after gemm<2>:  f32 cols [1024:2048) = 0.5*attn_out (clobbers Q,K; dead)
// d_ws (100 MiB):
//   [0,32Mi) rB | [32,64Mi) fB   -- dead after gemm<0>
//   [0,64Mi) S (overlays rB/fB)  -- written by gemm<1>
//   [64,96Mi) fT | [96,98Mi) WqT | [98,100Mi) WkT
// ---------------------------------------------------------------------------

typedef __attribute__((ext_vector_type(8))) short   bf16x8;
typedef __attribute__((ext_vector_type(4))) float   f32x4;

static __device__ __forceinline__ unsigned short f2b(float f) {
  __hip_bfloat16 h = __float2bfloat16(f);
  return *reinterpret_cast<unsigned short*>(&h);
}
static __device__ __forceinline__ float b2f(unsigned short u) {
  unsigned int x = ((unsigned int)u) << 16;
  return __uint_as_float(x);
}

#define GLOAD_LDS16(g, l) \
  __builtin_amdgcn_global_load_lds( \
      (const __attribute__((address_space(1))) void*)(g), \
      (__attribute__((address_space(3))) void*)(l), 16, 0, 0)

// ---------------------------------------------------------------------------
// Fused: out[:, 0:1024) = rgb (f32)  AND  rB = bf16(rgb).  One rgb read.
// ---------------------------------------------------------------------------
__global__ __launch_bounds__(256) void cast_copy_rgb(
    const float* rgb, __hip_bfloat16* rB, float* out) {
  size_t i = ((size_t)blockIdx.x * 256 + threadIdx.x) * 8;
  size_t m = i >> 10;
  int c = (int)(i & 1023);
  f32x4 a = *(const f32x4*)(rgb + i);
  f32x4 b = *(const f32x4*)(rgb + i + 4);
  *(f32x4*)(out + m * 2048 + c)     = a;
  *(f32x4*)(out + m * 2048 + c + 4) = b;
  union { bf16x8 v; unsigned short u[8]; } cv;
#pragma unroll
  for (int j = 0; j < 4; ++j) { cv.u[j] = f2b(a[j]); cv.u[4 + j] = f2b(b[j]); }
  *(bf16x8*)(rB + i) = cv.v;
}

// ---------------------------------------------------------------------------
// Transpose+cast f32 [R][C] -> bf16 [C][R].  z=0:Wq, z=1:Wk, z=2+b:freq[b]
// (freq blocks also emit row-major bf16 fB).
// ---------------------------------------------------------------------------
__global__ __launch_bounds__(256) void transpose_to_bf16(
    const float* Wq, const float* Wk, const float* freq,
    __hip_bfloat16* WqT, __hip_bfloat16* WkT, __hip_bfloat16* fT, __hip_bfloat16* fB) {
  int z = blockIdx.z;
  const float* src; __hip_bfloat16* dst; __hip_bfloat16* cpy = nullptr; int R, C;
  if (z == 0)      { src = Wq; dst = WqT; R = 1024; C = 1024; }
  else if (z == 1) { src = Wk; dst = WkT; R = 1024; C = 1024; }
  else {
    int b = z - 2;
    src = freq + (size_t)b*2048*1024; dst = fT + (size_t)b*1024*2048;
    cpy = fB + (size_t)b*2048*1024; R = 2048; C = 1024;
  }
  int r0 = blockIdx.x * 32, c0 = blockIdx.y * 32;
  if (r0 >= R) return;
  __shared__ float tile[32][33];
  int tx = threadIdx.x, ty = threadIdx.y;   // 32 x 8
#pragma unroll
  for (int i = 0; i < 4; ++i) {
    float v = src[(size_t)(r0 + ty + i*8) * C + c0 + tx];
    tile[ty + i*8][tx] = v;
    if (cpy) cpy[(size_t)(r0 + ty + i*8) * C + c0 + tx] = __float2bfloat16(v);
  }
  __syncthreads();
#pragma unroll
  for (int i = 0; i < 4; ++i)
    dst[(size_t)(c0 + ty + i*8) * R + r0 + tx] = __float2bfloat16(tile[tx][ty + i*8]);
}

// ---------------------------------------------------------------------------
// 256x256 8-phase GEMM, C = A * B^T.
// MODE 0: z=0: Q=rB*WqT^T -> slots[2048:3072]; z=1: K=fB*WkT^T -> [3072:4096].
// MODE 1: S = Q*K^T per batch (z) from d_out-packed Q,K -> bf16 S (ws).
// MODE 2: O = P*fT^T per batch -> f32 0.5*v into out cols [1024:2048).
//
// LDS: buf d at d*65536: A-half h at +h*16384, B-half h at +32768+h*16384.
// Each half = 16 subtiles of 1KiB ([16r][32c] bf16, inner_byte ^= ((row&8)<<2)).
// Tile t in buf[t&1].  Stage schedule (per iteration t):
//   P3: B0,B1(t+2)  (B region of buf[t&1] last read at P2)
//   P4: A0,A1(t+2)  (A region last read at P3); then vmcnt(8) drains tile
//       t+1's 8 loads, issued at t-1's P3/P4 -> 4-5 phase issue->wait gap.
// ---------------------------------------------------------------------------
template<int MODE>
__global__ __launch_bounds__(512, 2) void gemm256(
    const void* pA0, const void* pA1, const void* pB0, const void* pB1, void* pC) {
  constexpr int NX = (MODE == 0) ? 64 : 8;
  constexpr int NY = (MODE == 1) ? 8 : 4;
  constexpr int NZ = (MODE == 0) ? 2 : 8;
  constexpr int NT = (MODE == 2) ? 32 : 16;            // K / 64
  constexpr long LDA = (MODE == 0) ? 1024 : (MODE == 1) ? 4096 : 2048;
  constexpr long LDB = (MODE == 0) ? 1024 : (MODE == 1) ? 4096 : 2048;
  constexpr int NWG = NX * NY * NZ;                    // 512 / 512 / 256, %8==0

  // T1: bijective XCD swizzle
  int bid = blockIdx.x;
  int wg = (bid & 7) * (NWG >> 3) + (bid >> 3);
  int bx = wg % NX, by = (wg / NX) % NY, bz = wg / (NX * NY);
  const int row0 = bx * 256, col0 = by * 256;

  const int tid = threadIdx.x;
  const int wid = tid >> 6, l = tid & 63;
  const int wr = wid >> 2, wc = wid & 3;               // 2 x 4 wave grid
  const int lm = l & 15, lk = (l >> 4) & 3;

  const __hip_bfloat16 *A, *B;
  if constexpr (MODE == 0) {
    A = (const __hip_bfloat16*)(bz ? pA1 : pA0);
    B = (const __hip_bfloat16*)(bz ? pB1 : pB0);
  } else if constexpr (MODE == 1) {
    A = (const __hip_bfloat16*)pA0 + (size_t)bz*2048*4096 + 2048;  // Q
    B = (const __hip_bfloat16*)pA0 + (size_t)bz*2048*4096 + 3072;  // K
  } else {
    A = (const __hip_bfloat16*)pA0 + (size_t)bz*2048*2048;         // P
    B = (const __hip_bfloat16*)pB0 + (size_t)bz*1024*2048;         // freqT
  }

  __shared__ __align__(16) unsigned char lds[131072];

  // staging: lane l -> subtile inner row (l>>2), inverse-swizzled col
  const int srow = l >> 2;
  const int scol = ((l & 3) * 8) ^ ((l & 32) ? 16 : 0);
  const __hip_bfloat16* sA = A + (size_t)(row0 + wid*16 + srow) * LDA + scol;
  const __hip_bfloat16* sB = B + (size_t)(col0 + wid*16 + srow) * LDB + scol;

#define STAGE(mat, h, t) { \
    const __hip_bfloat16* _s = ((mat) ? sB : sA) \
        + (size_t)(h)*128*((mat) ? LDB : LDA) + (size_t)(t)*64; \
    unsigned _d = (unsigned)(((t)&1)*65536 + (mat)*32768 + (h)*16384 + wid*2048); \
    GLOAD_LDS16(_s,      lds + _d); \
    GLOAD_LDS16(_s + 32, lds + _d + 1024); }

  // ds_read: swizzled inner offset (same involution as the staged source)
  const int rdo = ((lm * 64) + (lk * 16)) ^ ((lm & 8) << 2);

  bf16x8 af[4][2];   // A quadrant frags (4 mi x 2 k-halves)
  bf16x8 bfr[4][2];  // all B frags for current tile
  f32x4 acc[8][4];
#pragma unroll
  for (int m = 0; m < 8; ++m)
#pragma unroll
    for (int n = 0; n < 4; ++n) acc[m][n] = (f32x4){0.f, 0.f, 0.f, 0.f};

#define LOAD_A(cur, qm) \
  _Pragma("unroll") for (int mi = 0; mi < 4; ++mi) \
  _Pragma("unroll") for (int s = 0; s < 2; ++s) \
    af[mi][s] = *(const bf16x8*)(lds + (cur)*65536 + wr*16384 \
                 + (((qm)*4 + mi)*2 + s)*1024 + rdo);
#define LOAD_B(cur, nlo) \
  _Pragma("unroll") for (int ni = 0; ni < 2; ++ni) \
  _Pragma("unroll") for (int s = 0; s < 2; ++s) \
    bfr[(nlo)+ni][s] = *(const bf16x8*)(lds + (cur)*65536 + 32768 + (wc>>1)*16384 \
                 + ((((wc&1)*4 + (nlo) + ni)*2) + s)*1024 + rdo);
#define MFMA_Q(qm, qn) \
  __builtin_amdgcn_s_setprio(1); \
  _Pragma("unroll") for (int mi = 0; mi < 4; ++mi) \
  _Pragma("unroll") for (int ni = 0; ni < 2; ++ni) \
  _Pragma("unroll") for (int s = 0; s < 2; ++s) \
    acc[(qm)*4 + mi][(qn)*2 + ni] = __builtin_amdgcn_mfma_f32_16x16x32_bf16( \
        af[mi][s], bfr[(qn)*2 + ni][s], acc[(qm)*4 + mi][(qn)*2 + ni], 0, 0, 0); \
  __builtin_amdgcn_s_setprio(0);
#define BARR __builtin_amdgcn_s_barrier();
#define LGKM0 asm volatile("s_waitcnt lgkmcnt(0)" ::: "memory");
#define VMW8 asm volatile("s_waitcnt vmcnt(8)" ::: "memory");
#define VMW0 asm volatile("s_waitcnt vmcnt(0)" ::: "memory");

  // prologue: tiles 0 and 1 fully staged (16 loads); wait tile0 (vmcnt(8))
  STAGE(0, 0, 0) STAGE(0, 1, 0) STAGE(1, 0, 0) STAGE(1, 1, 0)
  STAGE(0, 0, 1) STAGE(0, 1, 1) STAGE(1, 0, 1) STAGE(1, 1, 1)
  VMW8 BARR

  for (int g = 0; g < NT; ++g) {
    const int cur = g & 1;
    const int t2 = (g + 2 < NT) ? g + 2 : NT - 1;   // clamped re-stage writes
                                                    // identical data (benign)
    // P1
    LOAD_A(cur, 0) LOAD_B(cur, 0)
    BARR LGKM0 MFMA_Q(0, 0) BARR
    // P2
    LOAD_B(cur, 2)
    BARR LGKM0 MFMA_Q(0, 1) BARR
    // P3 (B region of buf[cur] free since P2's barrier)
    LOAD_A(cur, 1) STAGE(1, 0, t2) STAGE(1, 1, t2)
    BARR LGKM0 MFMA_Q(1, 0) BARR
    // P4 (A region of buf[cur] free since P3's barrier)
    STAGE(0, 0, t2) STAGE(0, 1, t2)
    BARR MFMA_Q(1, 1) VMW8 BARR
  }
  VMW0   // drain stray tail re-stage loads before LDS dealloc

  // ---- epilogue ----
#pragma unroll
  for (int m = 0; m < 8; ++m)
#pragma unroll
    for (int n = 0; n < 4; ++n)
#pragma unroll
      for (int r = 0; r < 4; ++r) {
        float v = acc[m][n][r];
        int grow = row0 + wr*128 + m*16 + lk*4 + r;
        int gcol = col0 + wc*64 + n*16 + lm;
        if constexpr (MODE == 0) {
          __hip_bfloat16* Cb = (__hip_bfloat16*)pC;
          Cb[(size_t)grow * 4096 + (bz ? 3072 : 2048) + gcol] = __float2bfloat16(v);
        } else if constexpr (MODE == 1) {
          __hip_bfloat16* Cb = (__hip_bfloat16*)pC + (size_t)bz*2048*2048;
          Cb[(size_t)grow * 2048 + gcol] = __float2bfloat16(v);
        } else {
          float* Cf = (float*)pC;
          Cf[((size_t)(bz*2048 + grow)) * 2048 + 1024 + gcol] = 0.5f * v;
        }
      }
#undef STAGE
#undef LOAD_A
#undef LOAD_B
#undef MFMA_Q
#undef BARR
#undef LGKM0
#undef VMW8
#undef VMW0
}

// ---------------------------------------------------------------------------
// Row softmax in place over S (bf16, 2048 per row), scale 1/32 folded in.
// ---------------------------------------------------------------------------
__global__ __launch_bounds__(256) void softmax_rows(__hip_bfloat16* S) {
  const int row = blockIdx.x;
  const int t = threadIdx.x;
  uint32_t* p32 = (uint32_t*)(S + (size_t)row * 2048);
  uint4 raw = ((const uint4*)p32)[t];
  uint32_t w[4] = {raw.x, raw.y, raw.z, raw.w};
  float x[8];
#pragma unroll
  for (int i = 0; i < 4; ++i) {
    x[2*i]   = b2f((unsigned short)(w[i] & 0xffffu)) * 0.03125f;
    x[2*i+1] = b2f((unsigned short)(w[i] >> 16))     * 0.03125f;
  }
  float mx = x[0];
#pragma unroll
  for (int i = 1; i < 8; ++i) mx = fmaxf(mx, x[i]);
  for (int o = 32; o; o >>= 1) mx = fmaxf(mx, __shfl_xor(mx, o));
  __shared__ float redm[4], reds[4];
  int wid = t >> 6;
  if ((t & 63) == 0) redm[wid] = mx;
  __syncthreads();
  mx = fmaxf(fmaxf(redm[0], redm[1]), fmaxf(redm[2], redm[3]));
  float e[8], s = 0.f;
#pragma unroll
  for (int i = 0; i < 8; ++i) { e[i] = __expf(x[i] - mx); s += e[i]; }
  for (int o = 32; o; o >>= 1) s += __shfl_xor(s, o);
  if ((t & 63) == 0) reds[wid] = s;
  __syncthreads();
  s = reds[0] + reds[1] + reds[2] + reds[3];
  float inv = 1.0f / s;
  uint32_t o[4];
#pragma unroll
  for (int i = 0; i < 4; ++i)
    o[i] = (uint32_t)f2b(e[2*i] * inv) | ((uint32_t)f2b(e[2*i+1] * inv) << 16);
  ((uint4*)p32)[t] = make_uint4(o[0], o[1], o[2], o[3]);
}

// ---------------------------------------------------------------------------
extern "C" void kernel_launch(void* const* d_in, const int* in_sizes, int n_in,
                              void* d_out, int out_size, void* d_ws, size_t ws_size,
                              hipStream_t stream) {
  const float* rgb  = (const float*)d_in[0];
  const float* freq = (const float*)d_in[1];
  // d_in[2] = ifreq (dead), d_in[5] = Wv (dead)
  const float* Wq   = (const float*)d_in[3];
  const float* Wk   = (const float*)d_in[4];
  float* out = (float*)d_out;

  const size_t WS_NEED = (size_t)100 * 1024 * 1024;
  if (ws_size < WS_NEED) return;

  char* ws = (char*)d_ws;
  __hip_bfloat16* rB  = (__hip_bfloat16*)(ws);
  __hip_bfloat16* fB  = (__hip_bfloat16*)(ws + ((size_t)32 << 20));
  __hip_bfloat16* S   = (__hip_bfloat16*)(ws);                       // overlays rB/fB
  __hip_bfloat16* fT  = (__hip_bfloat16*)(ws + ((size_t)64 << 20));
  __hip_bfloat16* WqT = (__hip_bfloat16*)(ws + ((size_t)96 << 20));
  __hip_bfloat16* WkT = (__hip_bfloat16*)(ws + ((size_t)98 << 20));

  hipLaunchKernelGGL(cast_copy_rgb, dim3(8192), dim3(256), 0, stream, rgb, rB, out);
  hipLaunchKernelGGL(transpose_to_bf16, dim3(64, 32, 10), dim3(32, 8), 0, stream,
                     Wq, Wk, freq, WqT, WkT, fT, fB);
  hipLaunchKernelGGL((gemm256<0>), dim3(512), dim3(512), 0, stream,
                     (const void*)rB, (const void*)fB, (const void*)WqT, (const void*)WkT, (void*)out);
  hipLaunchKernelGGL((gemm256<1>), dim3(512), dim3(512), 0, stream,
                     (const void*)out, nullptr, nullptr, nullptr, (void*)S);
  hipLaunchKernelGGL(softmax_rows, dim3(16384), dim3(256), 0, stream, S);
  hipLaunchKernelGGL((gemm256<2>), dim3(256), dim3(512), 0, stream,
                     (const void*)S, nullptr, (const void*)fT, nullptr, (void*)out);
}

// Round 8
// 297.089 us; speedup vs baseline: 1.0888x; 1.0888x over previous
//
#include <hip/hip_runtime.h>
#include <hip/hip_bf16.h>
#include <stdint.h>

// ---------------------------------------------------------------------------
// CrossAttention: out = concat([rgb, 0.5 * softmax((rgb Wq)(freq Wk)^T/sqrt(D)) @ freq], -1)
// B=8, N=2048, D=E=1024.
// GEMMs: 256^2 tile, BK=64, 8 waves, 128KiB LDS 2-tile double buffer,
// st_16x32 XOR swizzle (T2, bank conflicts = 0 verified), REGISTER-PIPELINED
// 4-phase schedule: ds_reads issued one phase early so LDS reads overlap MFMA
// (compiler emits counted lgkmcnt), 1 barrier/phase, stages spread 1 half per
// phase (m196: fine interleave, never concentrate), vmcnt(2)+barrier at p3
// guarantees all waves' tile-(g+1) stages landed before p4's early reads.
//
// d_out rows (2048 f32 = 4096 bf16 slots, m = b*2048+n):
//   cast_copy:      f32 [0:1024)  = rgb  (cols), slots [0:2048)
//   after gemm<0>:  Q bf16 slots [2048:3072], K bf16 slots [3072:4096]
//   after gemm<2>:  f32 cols [1024:2048) = 0.5*attn_out (clobbers Q,K; dead)
// d_ws (100 MiB):
//   [0,32Mi) rB | [32,64Mi) fB   -- dead after gemm<0>
//   [0,64Mi) S (overlays rB/fB)  -- written by gemm<1>
//   [64,96Mi) fT | [96,98Mi) WqT | [98,100Mi) WkT
// ---------------------------------------------------------------------------

typedef __attribute__((ext_vector_type(8))) short   bf16x8;
typedef __attribute__((ext_vector_type(4))) float   f32x4;

static __device__ __forceinline__ unsigned short f2b(float f) {
  __hip_bfloat16 h = __float2bfloat16(f);
  return *reinterpret_cast<unsigned short*>(&h);
}
static __device__ __forceinline__ float b2f(unsigned short u) {
  unsigned int x = ((unsigned int)u) << 16;
  return __uint_as_float(x);
}

#define GLOAD_LDS16(g, l) \
  __builtin_amdgcn_global_load_lds( \
      (const __attribute__((address_space(1))) void*)(g), \
      (__attribute__((address_space(3))) void*)(l), 16, 0, 0)

// ---------------------------------------------------------------------------
// Fused: out[:, 0:1024) = rgb (f32)  AND  rB = bf16(rgb).  One rgb read.
// ---------------------------------------------------------------------------
__global__ __launch_bounds__(256) void cast_copy_rgb(
    const float* rgb, __hip_bfloat16* rB, float* out) {
  size_t i = ((size_t)blockIdx.x * 256 + threadIdx.x) * 8;
  size_t m = i >> 10;
  int c = (int)(i & 1023);
  f32x4 a = *(const f32x4*)(rgb + i);
  f32x4 b = *(const f32x4*)(rgb + i + 4);
  *(f32x4*)(out + m * 2048 + c)     = a;
  *(f32x4*)(out + m * 2048 + c + 4) = b;
  union { bf16x8 v; unsigned short u[8]; } cv;
#pragma unroll
  for (int j = 0; j < 4; ++j) { cv.u[j] = f2b(a[j]); cv.u[4 + j] = f2b(b[j]); }
  *(bf16x8*)(rB + i) = cv.v;
}

// ---------------------------------------------------------------------------
// Transpose+cast f32 [R][C] -> bf16 [C][R].  z=0:Wq, z=1:Wk, z=2+b:freq[b]
// (freq blocks also emit row-major bf16 fB).
// ---------------------------------------------------------------------------
__global__ __launch_bounds__(256) void transpose_to_bf16(
    const float* Wq, const float* Wk, const float* freq,
    __hip_bfloat16* WqT, __hip_bfloat16* WkT, __hip_bfloat16* fT, __hip_bfloat16* fB) {
  int z = blockIdx.z;
  const float* src; __hip_bfloat16* dst; __hip_bfloat16* cpy = nullptr; int R, C;
  if (z == 0)      { src = Wq; dst = WqT; R = 1024; C = 1024; }
  else if (z == 1) { src = Wk; dst = WkT; R = 1024; C = 1024; }
  else {
    int b = z - 2;
    src = freq + (size_t)b*2048*1024; dst = fT + (size_t)b*1024*2048;
    cpy = fB + (size_t)b*2048*1024; R = 2048; C = 1024;
  }
  int r0 = blockIdx.x * 32, c0 = blockIdx.y * 32;
  if (r0 >= R) return;
  __shared__ float tile[32][33];
  int tx = threadIdx.x, ty = threadIdx.y;   // 32 x 8
#pragma unroll
  for (int i = 0; i < 4; ++i) {
    float v = src[(size_t)(r0 + ty + i*8) * C + c0 + tx];
    tile[ty + i*8][tx] = v;
    if (cpy) cpy[(size_t)(r0 + ty + i*8) * C + c0 + tx] = __float2bfloat16(v);
  }
  __syncthreads();
#pragma unroll
  for (int i = 0; i < 4; ++i)
    dst[(size_t)(c0 + ty + i*8) * R + r0 + tx] = __float2bfloat16(tile[tx][ty + i*8]);
}

// ---------------------------------------------------------------------------
// 256x256 register-pipelined GEMM, C = A * B^T.
// MODE 0: z=0: Q=rB*WqT^T -> slots[2048:3072]; z=1: K=fB*WkT^T -> [3072:4096].
// MODE 1: S = Q*K^T per batch (z) from d_out-packed Q,K -> bf16 S (ws).
// MODE 2: O = P*fT^T per batch -> f32 0.5*v into out cols [1024:2048).
//
// LDS: buf d at d*65536: A-half h at +h*16384, B-half h at +32768+h*16384.
// Each half = 16 subtiles of 1KiB ([16r][32c] bf16, inner_byte ^= ((row&8)<<2)).
// Tile t in buf[t&1].
// Per-tile phase schedule (reads issued ONE PHASE EARLY, overlap with MFMA):
//   p1: rd B23(g)      | stage A1(g+1)->other | Q00 (uses aLo/b01 rd at p4(g-1))
//   p2: rd Ahi(g)      | stage B1(g+1)->other | Q01
//   p3:                | stage B0(g+2)->cur   | Q10 | vmcnt(2) barrier
//   p4: rd aLo,b01(g+1)| stage A0(g+2)->cur   | Q11
// vmcnt(2)@p3 leaves only B0(g+2) in flight -> all 4 halves of g+1 landed
// (per-wave drain + barrier = collective guarantee) before p4's early reads.
// ---------------------------------------------------------------------------
template<int MODE>
__global__ __launch_bounds__(512, 2) void gemm256(
    const void* pA0, const void* pA1, const void* pB0, const void* pB1, void* pC) {
  constexpr int NX = (MODE == 0) ? 64 : 8;
  constexpr int NY = (MODE == 1) ? 8 : 4;
  constexpr int NZ = (MODE == 0) ? 2 : 8;
  constexpr int NT = (MODE == 2) ? 32 : 16;            // K / 64
  constexpr long LDA = (MODE == 0) ? 1024 : (MODE == 1) ? 4096 : 2048;
  constexpr long LDB = (MODE == 0) ? 1024 : (MODE == 1) ? 4096 : 2048;
  constexpr int NWG = NX * NY * NZ;                    // 512 / 512 / 256, %8==0

  // T1: bijective XCD swizzle
  int bid = blockIdx.x;
  int wg = (bid & 7) * (NWG >> 3) + (bid >> 3);
  int bx = wg % NX, by = (wg / NX) % NY, bz = wg / (NX * NY);
  const int row0 = bx * 256, col0 = by * 256;

  const int tid = threadIdx.x;
  const int wid = tid >> 6, l = tid & 63;
  const int wr = wid >> 2, wc = wid & 3;               // 2 x 4 wave grid
  const int lm = l & 15, lk = (l >> 4) & 3;

  const __hip_bfloat16 *A, *B;
  if constexpr (MODE == 0) {
    A = (const __hip_bfloat16*)(bz ? pA1 : pA0);
    B = (const __hip_bfloat16*)(bz ? pB1 : pB0);
  } else if constexpr (MODE == 1) {
    A = (const __hip_bfloat16*)pA0 + (size_t)bz*2048*4096 + 2048;  // Q
    B = (const __hip_bfloat16*)pA0 + (size_t)bz*2048*4096 + 3072;  // K
  } else {
    A = (const __hip_bfloat16*)pA0 + (size_t)bz*2048*2048;         // P
    B = (const __hip_bfloat16*)pB0 + (size_t)bz*1024*2048;         // freqT
  }

  __shared__ __align__(16) unsigned char lds[131072];

  // staging: lane l -> subtile inner row (l>>2), inverse-swizzled col
  const int srow = l >> 2;
  const int scol = ((l & 3) * 8) ^ ((l & 32) ? 16 : 0);
  const __hip_bfloat16* sA = A + (size_t)(row0 + wid*16 + srow) * LDA + scol;
  const __hip_bfloat16* sB = B + (size_t)(col0 + wid*16 + srow) * LDB + scol;

#define STAGE(mat, h, t) { \
    const __hip_bfloat16* _s = ((mat) ? sB : sA) \
        + (size_t)(h)*128*((mat) ? LDB : LDA) + (size_t)(t)*64; \
    unsigned _d = (unsigned)(((t)&1)*65536 + (mat)*32768 + (h)*16384 + wid*2048); \
    GLOAD_LDS16(_s,      lds + _d); \
    GLOAD_LDS16(_s + 32, lds + _d + 1024); }

  // ds_read: swizzled inner offset (same involution as the staged source)
  const int rdo = ((lm * 64) + (lk * 16)) ^ ((lm & 8) << 2);

  bf16x8 aLo[4][2], aHi[4][2];   // A quadrant frags (qm=0 / qm=1)
  bf16x8 b01[2][2], b23[2][2];   // B frag pairs
  f32x4 acc[8][4];
#pragma unroll
  for (int m = 0; m < 8; ++m)
#pragma unroll
    for (int n = 0; n < 4; ++n) acc[m][n] = (f32x4){0.f, 0.f, 0.f, 0.f};

#define LOAD_ALO(c) \
  _Pragma("unroll") for (int mi = 0; mi < 4; ++mi) \
  _Pragma("unroll") for (int s = 0; s < 2; ++s) \
    aLo[mi][s] = *(const bf16x8*)(lds + (c)*65536 + wr*16384 \
                 + ((mi*2) + s)*1024 + rdo);
#define LOAD_AHI(c) \
  _Pragma("unroll") for (int mi = 0; mi < 4; ++mi) \
  _Pragma("unroll") for (int s = 0; s < 2; ++s) \
    aHi[mi][s] = *(const bf16x8*)(lds + (c)*65536 + wr*16384 \
                 + (((4 + mi)*2) + s)*1024 + rdo);
#define LOAD_B01(c) \
  _Pragma("unroll") for (int ni = 0; ni < 2; ++ni) \
  _Pragma("unroll") for (int s = 0; s < 2; ++s) \
    b01[ni][s] = *(const bf16x8*)(lds + (c)*65536 + 32768 + (wc>>1)*16384 \
                 + ((((wc&1)*4 + ni)*2) + s)*1024 + rdo);
#define LOAD_B23(c) \
  _Pragma("unroll") for (int ni = 0; ni < 2; ++ni) \
  _Pragma("unroll") for (int s = 0; s < 2; ++s) \
    b23[ni][s] = *(const bf16x8*)(lds + (c)*65536 + 32768 + (wc>>1)*16384 \
                 + ((((wc&1)*4 + 2 + ni)*2) + s)*1024 + rdo);

#define MFMA_Q(af, bf, mo, no) \
  __builtin_amdgcn_s_setprio(1); \
  _Pragma("unroll") for (int mi = 0; mi < 4; ++mi) \
  _Pragma("unroll") for (int ni = 0; ni < 2; ++ni) \
  _Pragma("unroll") for (int s = 0; s < 2; ++s) \
    acc[(mo) + mi][(no) + ni] = __builtin_amdgcn_mfma_f32_16x16x32_bf16( \
        af[mi][s], bf[ni][s], acc[(mo) + mi][(no) + ni], 0, 0, 0); \
  __builtin_amdgcn_s_setprio(0);
#define BARR __builtin_amdgcn_s_barrier();
#define VMW2 asm volatile("s_waitcnt vmcnt(2)" ::: "memory");
#define VMW0 asm volatile("s_waitcnt vmcnt(0)" ::: "memory");

  // ---- prologue: tile0 all 4 halves + B0(1); drain tile0; prime reads ----
  STAGE(1, 0, 0) STAGE(0, 0, 0) STAGE(0, 1, 0) STAGE(1, 1, 0)
  STAGE(1, 0, 1)
  VMW2 BARR
  LOAD_ALO(0) LOAD_B01(0)
  STAGE(0, 0, 1)

  for (int g = 0; g < NT - 1; ++g) {
    const int cur = g & 1;
    const int nxt = cur ^ 1;
    const int tc2 = (g + 2 < NT) ? g + 2 : NT - 1;   // clamped re-stage writes
                                                     // identical data (benign)
    // p1
    LOAD_B23(cur) STAGE(0, 1, g + 1)
    MFMA_Q(aLo, b01, 0, 0) BARR
    // p2
    LOAD_AHI(cur) STAGE(1, 1, g + 1)
    MFMA_Q(aLo, b23, 0, 2) BARR
    // p3: vmcnt(2)+barrier -> all waves' tile-(g+1) stages landed
    STAGE(1, 0, tc2)
    MFMA_Q(aHi, b01, 4, 0) VMW2 BARR
    // p4: early reads of tile g+1 (other buf) overlap Q11
    LOAD_ALO(nxt) LOAD_B01(nxt) STAGE(0, 0, tc2)
    MFMA_Q(aHi, b23, 4, 2) BARR
  }
  // ---- peel: last tile, no stages / no next-tile reads ----
  {
    const int cur = (NT - 1) & 1;
    LOAD_B23(cur)
    MFMA_Q(aLo, b01, 0, 0)
    LOAD_AHI(cur)
    MFMA_Q(aLo, b23, 0, 2)
    MFMA_Q(aHi, b01, 4, 0)
    MFMA_Q(aHi, b23, 4, 2)
  }
  VMW0   // drain tail dup-stage loads before exit

  // ---- epilogue ----
#pragma unroll
  for (int m = 0; m < 8; ++m)
#pragma unroll
    for (int n = 0; n < 4; ++n)
#pragma unroll
      for (int r = 0; r < 4; ++r) {
        float v = acc[m][n][r];
        int grow = row0 + wr*128 + m*16 + lk*4 + r;
        int gcol = col0 + wc*64 + n*16 + lm;
        if constexpr (MODE == 0) {
          __hip_bfloat16* Cb = (__hip_bfloat16*)pC;
          Cb[(size_t)grow * 4096 + (bz ? 3072 : 2048) + gcol] = __float2bfloat16(v);
        } else if constexpr (MODE == 1) {
          __hip_bfloat16* Cb = (__hip_bfloat16*)pC + (size_t)bz*2048*2048;
          Cb[(size_t)grow * 2048 + gcol] = __float2bfloat16(v);
        } else {
          float* Cf = (float*)pC;
          Cf[((size_t)(bz*2048 + grow)) * 2048 + 1024 + gcol] = 0.5f * v;
        }
      }
#undef STAGE
#undef LOAD_ALO
#undef LOAD_AHI
#undef LOAD_B01
#undef LOAD_B23
#undef MFMA_Q
#undef BARR
#undef VMW2
#undef VMW0
}

// ---------------------------------------------------------------------------
// Row softmax in place over S (bf16, 2048 per row), scale 1/32 folded in.
// ---------------------------------------------------------------------------
__global__ __launch_bounds__(256) void softmax_rows(__hip_bfloat16* S) {
  const int row = blockIdx.x;
  const int t = threadIdx.x;
  uint32_t* p32 = (uint32_t*)(S + (size_t)row * 2048);
  uint4 raw = ((const uint4*)p32)[t];
  uint32_t w[4] = {raw.x, raw.y, raw.z, raw.w};
  float x[8];
#pragma unroll
  for (int i = 0; i < 4; ++i) {
    x[2*i]   = b2f((unsigned short)(w[i] & 0xffffu)) * 0.03125f;
    x[2*i+1] = b2f((unsigned short)(w[i] >> 16))     * 0.03125f;
  }
  float mx = x[0];
#pragma unroll
  for (int i = 1; i < 8; ++i) mx = fmaxf(mx, x[i]);
  for (int o = 32; o; o >>= 1) mx = fmaxf(mx, __shfl_xor(mx, o));
  __shared__ float redm[4], reds[4];
  int wid = t >> 6;
  if ((t & 63) == 0) redm[wid] = mx;
  __syncthreads();
  mx = fmaxf(fmaxf(redm[0], redm[1]), fmaxf(redm[2], redm[3]));
  float e[8], s = 0.f;
#pragma unroll
  for (int i = 0; i < 8; ++i) { e[i] = __expf(x[i] - mx); s += e[i]; }
  for (int o = 32; o; o >>= 1) s += __shfl_xor(s, o);
  if ((t & 63) == 0) reds[wid] = s;
  __syncthreads();
  s = reds[0] + reds[1] + reds[2] + reds[3];
  float inv = 1.0f / s;
  uint32_t o[4];
#pragma unroll
  for (int i = 0; i < 4; ++i)
    o[i] = (uint32_t)f2b(e[2*i] * inv) | ((uint32_t)f2b(e[2*i+1] * inv) << 16);
  ((uint4*)p32)[t] = make_uint4(o[0], o[1], o[2], o[3]);
}

// ---------------------------------------------------------------------------
extern "C" void kernel_launch(void* const* d_in, const int* in_sizes, int n_in,
                              void* d_out, int out_size, void* d_ws, size_t ws_size,
                              hipStream_t stream) {
  const float* rgb  = (const float*)d_in[0];
  const float* freq = (const float*)d_in[1];
  // d_in[2] = ifreq (dead), d_in[5] = Wv (dead)
  const float* Wq   = (const float*)d_in[3];
  const float* Wk   = (const float*)d_in[4];
  float* out = (float*)d_out;

  const size_t WS_NEED = (size_t)100 * 1024 * 1024;
  if (ws_size < WS_NEED) return;

  char* ws = (char*)d_ws;
  __hip_bfloat16* rB  = (__hip_bfloat16*)(ws);
  __hip_bfloat16* fB  = (__hip_bfloat16*)(ws + ((size_t)32 << 20));
  __hip_bfloat16* S   = (__hip_bfloat16*)(ws);                       // overlays rB/fB
  __hip_bfloat16* fT  = (__hip_bfloat16*)(ws + ((size_t)64 << 20));
  __hip_bfloat16* WqT = (__hip_bfloat16*)(ws + ((size_t)96 << 20));
  __hip_bfloat16* WkT = (__hip_bfloat16*)(ws + ((size_t)98 << 20));

  hipLaunchKernelGGL(cast_copy_rgb, dim3(8192), dim3(256), 0, stream, rgb, rB, out);
  hipLaunchKernelGGL(transpose_to_bf16, dim3(64, 32, 10), dim3(32, 8), 0, stream,
                     Wq, Wk, freq, WqT, WkT, fT, fB);
  hipLaunchKernelGGL((gemm256<0>), dim3(512), dim3(512), 0, stream,
                     (const void*)rB, (const void*)fB, (const void*)WqT, (const void*)WkT, (void*)out);
  hipLaunchKernelGGL((gemm256<1>), dim3(512), dim3(512), 0, stream,
                     (const void*)out, nullptr, nullptr, nullptr, (void*)S);
  hipLaunchKernelGGL(softmax_rows, dim3(16384), dim3(256), 0, stream, S);
  hipLaunchKernelGGL((gemm256<2>), dim3(256), dim3(512), 0, stream,
                     (const void*)S, nullptr, (const void*)fT, nullptr, (void*)out);
}